// Round 11
// baseline (143.524 us; speedup 1.0000x reference)
//
#include <hip/hip_runtime.h>

// Problem constants
#define Bn 8
#define Cn 64
#define Hn 128
#define Wn 128
#define On 64
#define K2n 9
#define HWn (Hn * Wn)          // 16384
#define OLP 20                 // offl row stride (floats): 18 + pad

typedef short bf16x8 __attribute__((ext_vector_type(8)));
typedef float f32x4  __attribute__((ext_vector_type(4)));

__device__ __forceinline__ unsigned f2bf(float f) {
    unsigned u = __float_as_uint(f);
    return (u + 0x7FFFu + ((u >> 16) & 1u)) >> 16;   // RNE fp32->bf16
}
__device__ __forceinline__ unsigned pkbf(float lo, float hi) {
    return f2bf(lo) | (f2bf(hi) << 16);              // verified form (R6)
}
__device__ __forceinline__ float bflo(unsigned u) { return __uint_as_float(u << 16); }
__device__ __forceinline__ float bfhi(unsigned u) { return __uint_as_float(u & 0xFFFF0000u); }

// R10-verified 3-op pack: round-half-up (+0x8000) per half + one v_perm
// assembling [hi.b3,hi.b2,lo.b3,lo.b2].  (+-1 ulp vs RNE on exact ties only)
__device__ __forceinline__ unsigned pkbf2(float lo, float hi) {
    const unsigned rlo = __float_as_uint(lo) + 0x8000u;
    const unsigned rhi = __float_as_uint(hi) + 0x8000u;
    return __builtin_amdgcn_perm(rhi, rlo, 0x07060302u);
}

// ---------------------------------------------------------------------------
// prep: blocks [0,2048): transpose x NCHW fp32 -> xT NHWC bf16-pair.
//       blocks [2048,2200): repack weight + w_off into MFMA B-frag order
//       (wt2[slot][lane][8], slot=(k*2+ks)*4+t, o=t*16+(lane&15),
//        c=ks*32+(lane>>4)*8+j; woffr same with slot=ks*2+t, o>=18 -> 0).
// ---------------------------------------------------------------------------
__global__ __launch_bounds__(256) void prep_kernel(
        const float* __restrict__ x,
        const float* __restrict__ w,
        const float* __restrict__ w_off,
        unsigned* __restrict__ xT,
        unsigned short* __restrict__ wt2,
        unsigned short* __restrict__ woffr) {
    const int tid = threadIdx.x;
    const int bid = blockIdx.x;

    if (bid >= 2048) {                           // ---- weight repack ----
        int i = (bid - 2048) * 256 + tid;        // 38912 = 152*256 exactly
        if (i < K2n * On * Cn) {
            int j    = i & 7;
            int lane = (i >> 3) & 63;
            int slot = i >> 9;
            int t  = slot & 3;
            int ks = (slot >> 2) & 1;
            int k  = slot >> 3;
            int o  = t * 16 + (lane & 15);
            int c  = ks * 32 + (lane >> 4) * 8 + j;
            wt2[i] = (unsigned short)f2bf(w[o * (Cn * K2n) + c * K2n + k]);
        } else {
            int idx  = i - K2n * On * Cn;        // < 2048
            int j    = idx & 7;
            int lane = (idx >> 3) & 63;
            int slot = idx >> 9;                 // 0..3 = ks*2 + t
            int t  = slot & 1;
            int ks = slot >> 1;
            int o  = t * 16 + (lane & 15);
            int c  = ks * 32 + (lane >> 4) * 8 + j;
            woffr[idx] = (o < 18) ? (unsigned short)f2bf(w_off[o * Cn + c]) : 0;
        }
        return;
    }

    // ---- transpose: 64px x 64ch tile ----
    __shared__ float tile[64 * 65];
    const int b   = bid >> 8;
    const int px0 = (bid & 255) << 6;

    {   // float4 reads: thread (c, pq) loads px [pq*16, pq*16+16) of channel c
        const int c = tid >> 2, pq = tid & 3;
        const float4* xp4 = (const float4*)(x + (size_t)b * (Cn * HWn)
                                              + (size_t)c * HWn + px0 + pq * 16);
        float4 v[4];
#pragma unroll
        for (int i = 0; i < 4; i++) v[i] = xp4[i];
#pragma unroll
        for (int i = 0; i < 16; i++)
            tile[(pq * 16 + i) * 65 + c] = (&v[0].x)[i];
    }
    __syncthreads();
    {   // pack + coalesced NHWC write
        const int c2 = tid & 31, r = tid >> 5;
        unsigned* dst = xT + ((size_t)b * HWn + px0) * 32;
#pragma unroll
        for (int j = 0; j < 8; j++) {
            const int p = j * 8 + r;
            dst[p * 32 + c2] = pkbf(tile[p * 65 + c2 * 2], tile[p * 65 + c2 * 2 + 1]);
        }
    }
}

// ---------------------------------------------------------------------------
// Main kernel.  Wave owns 16 px.
//
// R11 structure: ZERO sync points in the k-loop.
//  - Producer lanes are PAIR-MAJOR: m=(lane>>1)&15, c2=(lane&1)|((lane>>4)&2).
//    Lane pairs (2m,2m+1) read contiguous 32B (half the 64B merge of the old
//    sp-major map -- accepted cost), and crucially the producer of (m,c2)
//    sits in the SAME 32-lane half as its consumer lane d=(q<<4)|sp with
//    (m=sp, c2=q):  src = (d&32) | (sp<<1) | (q&1).
//  - Redistribution via 8x ds_bpermute_b32 with that src index (x4 bytes).
//    Because src and dest always share a half AND the half bit is explicit,
//    the result is identical whether gfx950's wave64 bpermute is full-
//    crossbar or half-restricted -- correct under BOTH semantics.
//  - This deletes: the chunk LDS tile (18.4 KB), the per-k lgkmcnt(0)
//    drain, the wtl stage (16.4 KB) and its per-k __syncthreads.  wt2
//    B-frags load straight from L1 (R8-verified code; costs the measured
//    ~2 us, buys barrier-free scheduling).  LDS = offl 5120 B only; the
//    k-loop has no LDS aliasing, no barriers, no asm fences.
// Session ledger: f32x2 packed combine ABANDONED (only consistent cause of
// R1/R4/R5/R6 corruption; R3 proved it exact when scalarized).  Single-
// buffer LDS reuse abandoned with it.  pkbf2 + mktap-lite verified R10;
// u ping-pong verified R2/R8; offl hand-off (wave-private, one lgkm drain)
// verified R0-R10.
// ---------------------------------------------------------------------------
struct Tap { float w00, w01, w10, w11; int c00, c01, c10, c11; };

__device__ __forceinline__ Tap mktap(int k, float offy, float offx, int h, int w) {
    Tap s;
    const int kh = k / 3, kw = k - kh * 3;
    const float py  = (float)(h - 1 + kh) + offy;
    const float pxf = (float)(w - 1 + kw) + offx;
    const float y0f = floorf(py), x0f = floorf(pxf);
    const float wy1 = py - y0f, wx1 = pxf - x0f;
    const float wy0 = 1.f - wy1, wx0 = 1.f - wx1;
    const int y0 = (int)y0f, x0i = (int)x0f;
    const int y1 = y0 + 1,  x1 = x0i + 1;
    // R10-verified: unsigned-range validity + zeroed 1-D weights
    const float zy0 = ((unsigned)y0  < (unsigned)Hn) ? wy0 : 0.f;
    const float zy1 = ((unsigned)y1  < (unsigned)Hn) ? wy1 : 0.f;
    const float zx0 = ((unsigned)x0i < (unsigned)Wn) ? wx0 : 0.f;
    const float zx1 = ((unsigned)x1  < (unsigned)Wn) ? wx1 : 0.f;
    s.w00 = zy0 * zx0; s.w01 = zy0 * zx1;
    s.w10 = zy1 * zx0; s.w11 = zy1 * zx1;
    const int yc0 = min(max(y0, 0), Hn - 1), yc1 = min(max(y1, 0), Hn - 1);
    const int xc0 = min(max(x0i, 0), Wn - 1), xc1 = min(max(x1, 0), Wn - 1);
    s.c00 = (yc0 * Wn + xc0) * 32; s.c01 = (yc0 * Wn + xc1) * 32;
    s.c10 = (yc1 * Wn + xc0) * 32; s.c11 = (yc1 * Wn + xc1) * 32;
    return s;
}

// scalar bilinear combine FMAs (R0-verbatim) + 3-op perm pack (R10-verified)
__device__ __forceinline__ void combine4(unsigned* dst, const uint4* u, const Tap& s) {
#pragma unroll
    for (int i = 0; i < 4; i++) {
        const unsigned a = (&u[0].x)[i], b = (&u[1].x)[i];
        const unsigned c = (&u[2].x)[i], d = (&u[3].x)[i];
        const float slo = s.w00 * bflo(a) + s.w01 * bflo(b)
                        + s.w10 * bflo(c) + s.w11 * bflo(d);
        const float shi = s.w00 * bfhi(a) + s.w01 * bfhi(b)
                        + s.w10 * bfhi(c) + s.w11 * bfhi(d);
        dst[i] = pkbf2(slo, shi);
    }
}

__device__ __forceinline__ void gather8(uint4* u, const unsigned* xb,
                                        const Tap& s, int c2) {
    const unsigned* g00 = xb + s.c00 + c2 * 4;
    const unsigned* g01 = xb + s.c01 + c2 * 4;
    const unsigned* g10 = xb + s.c10 + c2 * 4;
    const unsigned* g11 = xb + s.c11 + c2 * 4;
    u[0] = *(const uint4*)g00;          // half 0: chunk c2   (ks=0)
    u[1] = *(const uint4*)g01;
    u[2] = *(const uint4*)g10;
    u[3] = *(const uint4*)g11;
    u[4] = *(const uint4*)(g00 + 16);   // half 1: chunk 4+c2 (ks=1)
    u[5] = *(const uint4*)(g01 + 16);
    u[6] = *(const uint4*)(g10 + 16);
    u[7] = *(const uint4*)(g11 + 16);
}

__global__ __launch_bounds__(256, 2) void dcn_kernel(
        const unsigned* __restrict__ xT,
        const unsigned short* __restrict__ wt2,
        const unsigned short* __restrict__ woffr,
        const float* __restrict__ b_off,
        float* __restrict__ out) {
    __shared__ float offl[4 * 16 * OLP];                       // 5120 B total LDS

    const int tid = threadIdx.x;
    const int bid = blockIdx.x;
    // XCD swizzle: bid&7 = image -> per-XCD L2 holds one 2.1MB bf16 image
    const int logical = ((bid & 7) << 8) | (bid >> 3);         // 2048 blocks
    const int b   = logical >> 8;
    const int hw0 = (logical & 255) << 6;

    const int lane = tid & 63;
    const int wv   = tid >> 6;
    const int q    = lane >> 4;        // consumer: chunk index / K-half group
    const int sp   = lane & 15;        // consumer + prologue pixel
    // producer PAIR-MAJOR map (R11): same-half as consumer by construction
    const int m    = (lane >> 1) & 15;             // producer pixel
    const int c2   = (lane & 1) | ((lane >> 4) & 2); // producer 16B chunk
    const int pix0 = hw0 + wv * 16;
    const int pix  = pix0 + sp;

    const unsigned* xb = xT + (size_t)b * (HWn * 32);          // uint = 2 channels

    // ---- offset conv via MFMA (R6-verified) ------------------------------
    {
        union { uint4 u; bf16x8 v; } aw0, aw1;
        aw0.u = *(const uint4*)(xb + pix * 32 + q * 4);
        aw1.u = *(const uint4*)(xb + pix * 32 + 16 + q * 4);
        f32x4 oa0 = (f32x4){0.f, 0.f, 0.f, 0.f};
        f32x4 oa1 = (f32x4){0.f, 0.f, 0.f, 0.f};
        const bf16x8 bo00 = *(const bf16x8*)(woffr + 0 * 512 + lane * 8);
        const bf16x8 bo01 = *(const bf16x8*)(woffr + 1 * 512 + lane * 8);
        const bf16x8 bo10 = *(const bf16x8*)(woffr + 2 * 512 + lane * 8);
        const bf16x8 bo11 = *(const bf16x8*)(woffr + 3 * 512 + lane * 8);
        oa0 = __builtin_amdgcn_mfma_f32_16x16x32_bf16(aw0.v, bo00, oa0, 0, 0, 0);
        oa1 = __builtin_amdgcn_mfma_f32_16x16x32_bf16(aw0.v, bo01, oa1, 0, 0, 0);
        oa0 = __builtin_amdgcn_mfma_f32_16x16x32_bf16(aw1.v, bo10, oa0, 0, 0, 0);
        oa1 = __builtin_amdgcn_mfma_f32_16x16x32_bf16(aw1.v, bo11, oa1, 0, 0, 0);
        const int oc = lane & 15, rg = lane >> 4;
        float* ol = offl + wv * (16 * OLP);
        const float bo_a = b_off[oc];
#pragma unroll
        for (int r = 0; r < 4; r++)
            ol[(rg * 4 + r) * OLP + oc] = oa0[r] + bo_a;
        if (oc < 2) {
            const float bo_b = b_off[16 + oc];
#pragma unroll
            for (int r = 0; r < 4; r++)
                ol[(rg * 4 + r) * OLP + 16 + oc] = oa1[r] + bo_b;
        }
    }
    // per-wave LDS hand-off (offl is wave-private; verified R0-R10)
    asm volatile("s_waitcnt lgkmcnt(0)" ::: "memory");

    // hoist this lane's 18 offsets (pixel m) into registers (R2/R7-verified)
    const float* olp = offl + wv * (16 * OLP) + m * OLP;
    float off[18];
#pragma unroll
    for (int i = 0; i < 9; i++) {
        const float2 o2 = *(const float2*)(olp + 2 * i);
        off[2 * i]     = o2.x;
        off[2 * i + 1] = o2.y;
    }

    // producer-side state: this lane samples pixel m
    const int pixm = pix0 + m;
    const int hm = pixm >> 7;
    const int wm = pixm & 127;

    // bpermute byte-index: dest lane d=(q<<4)|sp pulls from src lane
    // (d&32)|(sp<<1)|(q&1) -- same half, explicit half bit => identical
    // result under full-wave64 OR half-restricted bpermute semantics
    const int bidx = ((lane & 32) | (sp << 1) | (q & 1)) << 2;

    f32x4 acc[4];
#pragma unroll
    for (int t = 0; t < 4; t++) acc[t] = (f32x4){0.f, 0.f, 0.f, 0.f};

    // ---- software pipeline: gather regs for k=0 (R2/R8-verified) ---------
    uint4 u[2][8];                     // ping-pong gather state
    Tap   tp[2];
    tp[0] = mktap(0, off[0], off[1], hm, wm);
    gather8(u[0], xb, tp[0], c2);

#pragma unroll
    for (int k = 0; k < K2n; k++) {
        const int cur = k & 1, nxt = cur ^ 1;

        // issue k+1's gathers first (latency hides under combine+MFMA of k)
        if (k + 1 < K2n) {
            tp[nxt] = mktap(k + 1, off[2 * k + 2], off[2 * k + 3], hm, wm);
            gather8(u[nxt], xb, tp[nxt], c2);
        }

        // B-frags for k direct from L1 (R8-verified pattern; L2-resident)
        const unsigned short* bp = wt2 + (size_t)(k * 8) * 512 + lane * 8;
        bf16x8 wtr[8];
#pragma unroll
        for (int t = 0; t < 8; t++) wtr[t] = *(const bf16x8*)(bp + t * 512);

        // combine current k's taps + pack
        unsigned A0[4], A1[4];
        combine4(A0, &u[cur][0], tp[cur]);  // channels c2*8..+8      (ks=0)
        combine4(A1, &u[cur][4], tp[cur]);  // channels 32+c2*8..+8   (ks=1)

        // redistribute via register lane-permute: no LDS, no drain, no
        // barrier; dest gets all 4 dwords of each half from one src lane
        union { unsigned w[4]; bf16x8 v; } f0, f1;
#pragma unroll
        for (int i = 0; i < 4; i++) {
            f0.w[i] = (unsigned)__builtin_amdgcn_ds_bpermute(bidx, (int)A0[i]);
            f1.w[i] = (unsigned)__builtin_amdgcn_ds_bpermute(bidx, (int)A1[i]);
        }

#pragma unroll
        for (int t = 0; t < 4; t++) {
            acc[t] = __builtin_amdgcn_mfma_f32_16x16x32_bf16(f0.v, wtr[t],     acc[t], 0, 0, 0);
            acc[t] = __builtin_amdgcn_mfma_f32_16x16x32_bf16(f1.v, wtr[4 + t], acc[t], 0, 0, 0);
        }
    }

    // ---- epilogue: C/D layout col(=o)=lane&15, row(=px)=(lane>>4)*4+r ----
    const int oc = lane & 15;
    const int rg = lane >> 4;
    float* ob = out + (size_t)b * (On * HWn) + pix0 + rg * 4;
#pragma unroll
    for (int t = 0; t < 4; t++) {
        const int o = t * 16 + oc;
        *(f32x4*)(ob + (size_t)o * HWn) = acc[t];
    }
}

// ---------------------------------------------------------------------------
extern "C" void kernel_launch(void* const* d_in, const int* in_sizes, int n_in,
                              void* d_out, int out_size, void* d_ws, size_t ws_size,
                              hipStream_t stream) {
    const float* x      = (const float*)d_in[0];   // (8,64,128,128)
    const float* weight = (const float*)d_in[1];   // (64,64,3,3)
    const float* w_off  = (const float*)d_in[2];   // (18,64)
    const float* b_off  = (const float*)d_in[3];   // (18,)
    float* out = (float*)d_out;                    // (8,64,128,128)

    // workspace: xT 16 MB | wt2 73728 B | woffr 4096 B
    unsigned*       xT    = (unsigned*)d_ws;
    unsigned short* wt2   = (unsigned short*)((char*)d_ws + 16777216);
    unsigned short* woffr = (unsigned short*)((char*)d_ws + 16777216 + 73728);

    prep_kernel<<<2200, 256, 0, stream>>>(x, weight, w_off, xT, wt2, woffr);
    dcn_kernel<<<2048, 256, 0, stream>>>(xT, wt2, woffr, b_off, out);
}

// Round 12
// 124.856 us; speedup vs baseline: 1.1495x; 1.1495x over previous
//
#include <hip/hip_runtime.h>

// Problem constants
#define Bn 8
#define Cn 64
#define Hn 128
#define Wn 128
#define On 64
#define K2n 9
#define HWn (Hn * Wn)          // 16384
#define OLP 20                 // offl row stride (floats): 18 + pad
#define TLP 68                 // prep tile row stride (floats): 64 + 4 pad (16B-aligned rows)

typedef short bf16x8 __attribute__((ext_vector_type(8)));
typedef float f32x4  __attribute__((ext_vector_type(4)));

__device__ __forceinline__ unsigned f2bf(float f) {
    unsigned u = __float_as_uint(f);
    return (u + 0x7FFFu + ((u >> 16) & 1u)) >> 16;   // RNE fp32->bf16
}
__device__ __forceinline__ unsigned pkbf(float lo, float hi) {
    return f2bf(lo) | (f2bf(hi) << 16);              // verified form (R6)
}
__device__ __forceinline__ float bflo(unsigned u) { return __uint_as_float(u << 16); }
__device__ __forceinline__ float bfhi(unsigned u) { return __uint_as_float(u & 0xFFFF0000u); }

// R10-verified 3-op pack (dcn combine only; prep keeps exact RNE so xT bits
// are unchanged): round-half-up per half + one v_perm.
__device__ __forceinline__ unsigned pkbf2(float lo, float hi) {
    const unsigned rlo = __float_as_uint(lo) + 0x8000u;
    const unsigned rhi = __float_as_uint(hi) + 0x8000u;
    return __builtin_amdgcn_perm(rhi, rlo, 0x07060302u);
}

// ---------------------------------------------------------------------------
// prep: blocks [0,2048): transpose x NCHW fp32 -> xT NHWC bf16-pair.
//       blocks [2048,2200): repack weight + w_off into MFMA B-frag order.
//
// R12 transpose rewrite (xT bits identical to R0-R10): 4x4 micro-transpose
// in registers.  Phase A: thread (pg=tid&15, cq=tid>>4) loads float4 of 4 px
// for each of 4 channels (lanes 0-15 contiguous 256B per channel -> full
// merge), then writes 4 x b128 LDS rows [pg*4+j][cq*4..+3].  Start banks
// 4*((j*4? ...)+..) spread so each 16-lane wavefront phase covers all 32
// banks exactly once -> b128 floor, zero conflict.  Phase B: thread
// (cf4=tid&15, r=tid>>4) reads float4 [p][cf4*4..+3], packs 2 dwords (RNE),
// stores uint2 (lanes 0-15 contiguous 128B).  LDS ops/thread: 32 scalar ->
// 8 wide; stores 8 -> 4.
// ---------------------------------------------------------------------------
__global__ __launch_bounds__(256) void prep_kernel(
        const float* __restrict__ x,
        const float* __restrict__ w,
        const float* __restrict__ w_off,
        unsigned* __restrict__ xT,
        unsigned short* __restrict__ wt2,
        unsigned short* __restrict__ woffr) {
    const int tid = threadIdx.x;
    const int bid = blockIdx.x;

    if (bid >= 2048) {                           // ---- weight repack ----
        int i = (bid - 2048) * 256 + tid;        // 38912 = 152*256 exactly
        if (i < K2n * On * Cn) {
            int j    = i & 7;
            int lane = (i >> 3) & 63;
            int slot = i >> 9;
            int t  = slot & 3;
            int ks = (slot >> 2) & 1;
            int k  = slot >> 3;
            int o  = t * 16 + (lane & 15);
            int c  = ks * 32 + (lane >> 4) * 8 + j;
            wt2[i] = (unsigned short)f2bf(w[o * (Cn * K2n) + c * K2n + k]);
        } else {
            int idx  = i - K2n * On * Cn;        // < 2048
            int j    = idx & 7;
            int lane = (idx >> 3) & 63;
            int slot = idx >> 9;                 // 0..3 = ks*2 + t
            int t  = slot & 1;
            int ks = slot >> 1;
            int o  = t * 16 + (lane & 15);
            int c  = ks * 32 + (lane >> 4) * 8 + j;
            woffr[idx] = (o < 18) ? (unsigned short)f2bf(w_off[o * Cn + c]) : 0;
        }
        return;
    }

    // ---- transpose: 64px x 64ch tile, 4x4 register micro-transpose ----
    __shared__ __align__(16) float tile[64 * TLP];             // 17408 B
    const int b   = bid >> 8;
    const int px0 = (bid & 255) << 6;

    {   // phase A: (pg,cq) loads 4ch x 4px, writes 4 x b128 rows
        const int pg = tid & 15;           // 4-px group
        const int cq = tid >> 4;           // 4-ch group
        const float* xp = x + (size_t)b * (Cn * HWn) + px0 + pg * 4;
        float4 v[4];
#pragma unroll
        for (int i = 0; i < 4; i++)
            v[i] = *(const float4*)(xp + (size_t)(cq * 4 + i) * HWn);
#pragma unroll
        for (int j = 0; j < 4; j++)
            *(float4*)&tile[(pg * 4 + j) * TLP + cq * 4] =
                make_float4((&v[0].x)[j], (&v[1].x)[j],
                            (&v[2].x)[j], (&v[3].x)[j]);
    }
    __syncthreads();
    {   // phase B: (cf4,r) reads b128, packs 2 dwords (exact RNE), uint2 store
        const int cf4 = tid & 15;          // 4-channel group
        const int r   = tid >> 4;          // 0-15
        unsigned* dst = xT + ((size_t)b * HWn + px0) * 32;
#pragma unroll
        for (int j = 0; j < 4; j++) {
            const int p = j * 16 + r;
            const float4 t4 = *(const float4*)&tile[p * TLP + cf4 * 4];
            *(uint2*)(dst + p * 32 + cf4 * 2) =
                make_uint2(pkbf(t4.x, t4.y), pkbf(t4.z, t4.w));
        }
    }
}

// ---------------------------------------------------------------------------
// Main kernel: R10-VERBATIM (best verified: dcn 46.2 us).
// Wave owns 16 px.  Gather lanes SP-MAJOR (lane = m*4+c2): aligned lane-
// quads read contiguous 64B -> TA merges (R11 proved halving this merge
// costs ~17 us -- sp-major is non-negotiable).  Redistribution via R0-
// verbatim double-buffered wave-private chunk LDS tile (one lgkm clobber
// per k).  wt2 staged in LDS per block (R9), 16B-lane-stride copy (R10).
// pkbf2 pack + mktap-lite (R10-verified).  Offsets hoisted (R2/R7), offl
// aliases chunk storage across a __syncthreads (R7).
// Session ledger: f32x2 packed combine ABANDONED (only consistent cause of
// R1/R4/R5/R6 corruption); single-buffer LDS reuse abandoned with it.
// Same-half bpermute redistribution CORRECT but slower (R11: pair-major
// gather halves TA merge width).
// ---------------------------------------------------------------------------
struct Tap { float w00, w01, w10, w11; int c00, c01, c10, c11; };

__device__ __forceinline__ Tap mktap(int k, float offy, float offx, int h, int w) {
    Tap s;
    const int kh = k / 3, kw = k - kh * 3;
    const float py  = (float)(h - 1 + kh) + offy;
    const float pxf = (float)(w - 1 + kw) + offx;
    const float y0f = floorf(py), x0f = floorf(pxf);
    const float wy1 = py - y0f, wx1 = pxf - x0f;
    const float wy0 = 1.f - wy1, wx0 = 1.f - wx1;
    const int y0 = (int)y0f, x0i = (int)x0f;
    const int y1 = y0 + 1,  x1 = x0i + 1;
    const float zy0 = ((unsigned)y0  < (unsigned)Hn) ? wy0 : 0.f;
    const float zy1 = ((unsigned)y1  < (unsigned)Hn) ? wy1 : 0.f;
    const float zx0 = ((unsigned)x0i < (unsigned)Wn) ? wx0 : 0.f;
    const float zx1 = ((unsigned)x1  < (unsigned)Wn) ? wx1 : 0.f;
    s.w00 = zy0 * zx0; s.w01 = zy0 * zx1;
    s.w10 = zy1 * zx0; s.w11 = zy1 * zx1;
    const int yc0 = min(max(y0, 0), Hn - 1), yc1 = min(max(y1, 0), Hn - 1);
    const int xc0 = min(max(x0i, 0), Wn - 1), xc1 = min(max(x1, 0), Wn - 1);
    s.c00 = (yc0 * Wn + xc0) * 32; s.c01 = (yc0 * Wn + xc1) * 32;
    s.c10 = (yc1 * Wn + xc0) * 32; s.c11 = (yc1 * Wn + xc1) * 32;
    return s;
}

__device__ __forceinline__ void combine4(unsigned* dst, const uint4* u, const Tap& s) {
#pragma unroll
    for (int i = 0; i < 4; i++) {
        const unsigned a = (&u[0].x)[i], b = (&u[1].x)[i];
        const unsigned c = (&u[2].x)[i], d = (&u[3].x)[i];
        const float slo = s.w00 * bflo(a) + s.w01 * bflo(b)
                        + s.w10 * bflo(c) + s.w11 * bflo(d);
        const float shi = s.w00 * bfhi(a) + s.w01 * bfhi(b)
                        + s.w10 * bfhi(c) + s.w11 * bfhi(d);
        dst[i] = pkbf2(slo, shi);
    }
}

__device__ __forceinline__ void gather8(uint4* u, const unsigned* xb,
                                        const Tap& s, int c2) {
    const unsigned* g00 = xb + s.c00 + c2 * 4;
    const unsigned* g01 = xb + s.c01 + c2 * 4;
    const unsigned* g10 = xb + s.c10 + c2 * 4;
    const unsigned* g11 = xb + s.c11 + c2 * 4;
    u[0] = *(const uint4*)g00;          // half 0: chunk c2   (ks=0)
    u[1] = *(const uint4*)g01;
    u[2] = *(const uint4*)g10;
    u[3] = *(const uint4*)g11;
    u[4] = *(const uint4*)(g00 + 16);   // half 1: chunk 4+c2 (ks=1)
    u[5] = *(const uint4*)(g01 + 16);
    u[6] = *(const uint4*)(g10 + 16);
    u[7] = *(const uint4*)(g11 + 16);
}

__global__ __launch_bounds__(256, 2) void dcn_kernel(
        const unsigned* __restrict__ xT,
        const unsigned short* __restrict__ wt2,
        const unsigned short* __restrict__ woffr,
        const float* __restrict__ b_off,
        float* __restrict__ out) {
    // chunk tiles (first 5120 B double as offl during the prologue, R7-
    // verified) + double-buffered wt2 B-matrix stage (2 x 8192 B)
    __shared__ __align__(16) unsigned shmem[4][2][16 * 36];    // 18432 B
    __shared__ __align__(16) unsigned short wtl[2][8 * 512];   // 16384 B
    float* const offl = (float*)&shmem[0][0][0];               // prologue alias

    const int tid = threadIdx.x;
    const int bid = blockIdx.x;
    // XCD swizzle: bid&7 = image -> per-XCD L2 holds one 2.1MB bf16 image
    const int logical = ((bid & 7) << 8) | (bid >> 3);         // 2048 blocks
    const int b   = logical >> 8;
    const int hw0 = (logical & 255) << 6;

    const int lane = tid & 63;
    const int wv   = tid >> 6;
    const int q    = lane >> 4;        // consumer: chunk index / K-half group
    const int sp   = lane & 15;        // consumer + prologue pixel
    const int m    = lane >> 2;        // producer pixel (sp-major gather)
    const int c2   = lane & 3;         // producer 16B-chunk within 64B half
    const int pix0 = hw0 + wv * 16;
    const int pix  = pix0 + sp;

    const unsigned* xb = xT + (size_t)b * (HWn * 32);          // uint = 2 channels

    // ---- offset conv via MFMA (R6-verified) ------------------------------
    {
        union { uint4 u; bf16x8 v; } aw0, aw1;
        aw0.u = *(const uint4*)(xb + pix * 32 + q * 4);
        aw1.u = *(const uint4*)(xb + pix * 32 + 16 + q * 4);
        f32x4 oa0 = (f32x4){0.f, 0.f, 0.f, 0.f};
        f32x4 oa1 = (f32x4){0.f, 0.f, 0.f, 0.f};
        const bf16x8 bo00 = *(const bf16x8*)(woffr + 0 * 512 + lane * 8);
        const bf16x8 bo01 = *(const bf16x8*)(woffr + 1 * 512 + lane * 8);
        const bf16x8 bo10 = *(const bf16x8*)(woffr + 2 * 512 + lane * 8);
        const bf16x8 bo11 = *(const bf16x8*)(woffr + 3 * 512 + lane * 8);
        oa0 = __builtin_amdgcn_mfma_f32_16x16x32_bf16(aw0.v, bo00, oa0, 0, 0, 0);
        oa1 = __builtin_amdgcn_mfma_f32_16x16x32_bf16(aw0.v, bo01, oa1, 0, 0, 0);
        oa0 = __builtin_amdgcn_mfma_f32_16x16x32_bf16(aw1.v, bo10, oa0, 0, 0, 0);
        oa1 = __builtin_amdgcn_mfma_f32_16x16x32_bf16(aw1.v, bo11, oa1, 0, 0, 0);
        const int oc = lane & 15, rg = lane >> 4;
        float* ol = offl + wv * (16 * OLP);
        const float bo_a = b_off[oc];
#pragma unroll
        for (int r = 0; r < 4; r++)
            ol[(rg * 4 + r) * OLP + oc] = oa0[r] + bo_a;
        if (oc < 2) {
            const float bo_b = b_off[16 + oc];
#pragma unroll
            for (int r = 0; r < 4; r++)
                ol[(rg * 4 + r) * OLP + 16 + oc] = oa1[r] + bo_b;
        }
    }
    // stage wt2[k=0] into wtl[0] at 16B lane stride (R10-verified pattern)
    {
        const uint4* s0 = (const uint4*)(wt2);
        uint4* d0 = (uint4*)(&wtl[0][0]);
        d0[tid]       = s0[tid];
        d0[tid + 256] = s0[tid + 256];
    }
    asm volatile("s_waitcnt lgkmcnt(0)" ::: "memory");   // per-wave LDS hand-off

    // hoist this lane's 18 offsets (pixel m) into registers (R2/R7-verified)
    const float* olp = offl + wv * (16 * OLP) + m * OLP;
    float off[18];
#pragma unroll
    for (int i = 0; i < 9; i++) {
        const float2 o2 = *(const float2*)(olp + 2 * i);
        off[2 * i]     = o2.x;
        off[2 * i + 1] = o2.y;
    }

    // cross-wave barrier: all offl reads done before chunk writes; wtl[0]
    // staging visible to all waves
    __syncthreads();

    // producer-side state: this lane samples pixel m
    const int pixm = pix0 + m;
    const int hm = pixm >> 7;
    const int wm = pixm & 127;
    unsigned* cwv = &shmem[wv][0][0];                    // 2 x 576 dwords

    f32x4 acc[4];
#pragma unroll
    for (int t = 0; t < 4; t++) acc[t] = (f32x4){0.f, 0.f, 0.f, 0.f};

    // ---- software pipeline state: gather regs for k=0 (R2/R8-verified) ---
    uint4 u[2][8];                     // ping-pong gather state
    Tap   tp[2];
    tp[0] = mktap(0, off[0], off[1], hm, wm);
    gather8(u[0], xb, tp[0], c2);

#pragma unroll
    for (int k = 0; k < K2n; k++) {
        const int cur = k & 1, nxt = cur ^ 1;

        // stage wt2[k+1] -> wtl[nxt] + issue k+1's gathers (latency hides
        // under combine(k) + MFMA(k))
        if (k + 1 < K2n) {
            const uint4* sn = (const uint4*)(wt2 + (size_t)(k + 1) * 4096);
            uint4* dn = (uint4*)(&wtl[nxt][0]);
            dn[tid]       = sn[tid];
            dn[tid + 256] = sn[tid + 256];
            tp[nxt] = mktap(k + 1, off[2 * k + 2], off[2 * k + 3], hm, wm);
            gather8(u[nxt], xb, tp[nxt], c2);
        }

        // combine current k's taps + pack
        unsigned A0[4], A1[4];
        combine4(A0, &u[cur][0], tp[cur]);  // channels c2*8..+8      (ks=0)
        combine4(A1, &u[cur][4], tp[cur]);  // channels 32+c2*8..+8   (ks=1)

        // redistribute via double-buffered wave-private chunk LDS
        unsigned* cb = cwv + cur * 576;
        *(uint4*)(cb + m * 36 + c2 * 4)      = make_uint4(A0[0], A0[1], A0[2], A0[3]);
        *(uint4*)(cb + m * 36 + 16 + c2 * 4) = make_uint4(A1[0], A1[1], A1[2], A1[3]);

        // RAW: commit writes before frag reads (full compiler barrier too)
        asm volatile("s_waitcnt lgkmcnt(0)" ::: "memory");

        const bf16x8 af0 = *(const bf16x8*)(cb + sp * 36 + q * 4);
        const bf16x8 af1 = *(const bf16x8*)(cb + sp * 36 + 16 + q * 4);

        // B-frags from the block-shared LDS stage (R9-verified)
        const unsigned short* bl = &wtl[cur][lane * 8];
#pragma unroll
        for (int t = 0; t < 4; t++) {
            const bf16x8 b0 = *(const bf16x8*)(bl + t * 512);
            acc[t] = __builtin_amdgcn_mfma_f32_16x16x32_bf16(af0, b0, acc[t], 0, 0, 0);
            const bf16x8 b1 = *(const bf16x8*)(bl + (4 + t) * 512);
            acc[t] = __builtin_amdgcn_mfma_f32_16x16x32_bf16(af1, b1, acc[t], 0, 0, 0);
        }

        // publish wtl[nxt] + protect wtl[cur] (cross-barrier discipline)
        __syncthreads();
    }

    // ---- epilogue: C/D layout col(=o)=lane&15, row(=px)=(lane>>4)*4+r ----
    const int oc = lane & 15;
    const int rg = lane >> 4;
    float* ob = out + (size_t)b * (On * HWn) + pix0 + rg * 4;
#pragma unroll
    for (int t = 0; t < 4; t++) {
        const int o = t * 16 + oc;
        *(f32x4*)(ob + (size_t)o * HWn) = acc[t];
    }
}

// ---------------------------------------------------------------------------
extern "C" void kernel_launch(void* const* d_in, const int* in_sizes, int n_in,
                              void* d_out, int out_size, void* d_ws, size_t ws_size,
                              hipStream_t stream) {
    const float* x      = (const float*)d_in[0];   // (8,64,128,128)
    const float* weight = (const float*)d_in[1];   // (64,64,3,3)
    const float* w_off  = (const float*)d_in[2];   // (18,64)
    const float* b_off  = (const float*)d_in[3];   // (18,)
    float* out = (float*)d_out;                    // (8,64,128,128)

    // workspace: xT 16 MB | wt2 73728 B | woffr 4096 B
    unsigned*       xT    = (unsigned*)d_ws;
    unsigned short* wt2   = (unsigned short*)((char*)d_ws + 16777216);
    unsigned short* woffr = (unsigned short*)((char*)d_ws + 16777216 + 73728);

    prep_kernel<<<2200, 256, 0, stream>>>(x, weight, w_off, xT, wt2, woffr);
    dcn_kernel<<<2048, 256, 0, stream>>>(xT, wt2, woffr, b_off, out);
}

// Round 13
// 123.003 us; speedup vs baseline: 1.1668x; 1.0151x over previous
//
#include <hip/hip_runtime.h>

// Problem constants
#define Bn 8
#define Cn 64
#define Hn 128
#define Wn 128
#define On 64
#define K2n 9
#define HWn (Hn * Wn)          // 16384
#define OLP 20                 // offl row stride (floats): 18 + pad
#define TLP 68                 // prep tile row stride (floats): 64 + 4 pad

typedef short bf16x8 __attribute__((ext_vector_type(8)));
typedef float f32x4  __attribute__((ext_vector_type(4)));

__device__ __forceinline__ unsigned f2bf(float f) {
    unsigned u = __float_as_uint(f);
    return (u + 0x7FFFu + ((u >> 16) & 1u)) >> 16;   // RNE fp32->bf16
}
__device__ __forceinline__ unsigned pkbf(float lo, float hi) {
    return f2bf(lo) | (f2bf(hi) << 16);              // verified form (R6)
}
__device__ __forceinline__ float bflo(unsigned u) { return __uint_as_float(u << 16); }
__device__ __forceinline__ float bfhi(unsigned u) { return __uint_as_float(u & 0xFFFF0000u); }

// R10-verified 3-op pack (dcn combine only; prep keeps exact RNE so xT bits
// are unchanged): round-half-up per half + one v_perm.
__device__ __forceinline__ unsigned pkbf2(float lo, float hi) {
    const unsigned rlo = __float_as_uint(lo) + 0x8000u;
    const unsigned rhi = __float_as_uint(hi) + 0x8000u;
    return __builtin_amdgcn_perm(rhi, rlo, 0x07060302u);
}

// ---------------------------------------------------------------------------
// prep (R12-verified): blocks [0,2048): transpose x NCHW fp32 -> xT NHWC
// bf16-pair via 4x4 register micro-transpose.  blocks [2048,2200): repack
// weight + w_off into MFMA B-frag order.
// ---------------------------------------------------------------------------
__global__ __launch_bounds__(256) void prep_kernel(
        const float* __restrict__ x,
        const float* __restrict__ w,
        const float* __restrict__ w_off,
        unsigned* __restrict__ xT,
        unsigned short* __restrict__ wt2,
        unsigned short* __restrict__ woffr) {
    const int tid = threadIdx.x;
    const int bid = blockIdx.x;

    if (bid >= 2048) {                           // ---- weight repack ----
        int i = (bid - 2048) * 256 + tid;        // 38912 = 152*256 exactly
        if (i < K2n * On * Cn) {
            int j    = i & 7;
            int lane = (i >> 3) & 63;
            int slot = i >> 9;
            int t  = slot & 3;
            int ks = (slot >> 2) & 1;
            int k  = slot >> 3;
            int o  = t * 16 + (lane & 15);
            int c  = ks * 32 + (lane >> 4) * 8 + j;
            wt2[i] = (unsigned short)f2bf(w[o * (Cn * K2n) + c * K2n + k]);
        } else {
            int idx  = i - K2n * On * Cn;        // < 2048
            int j    = idx & 7;
            int lane = (idx >> 3) & 63;
            int slot = idx >> 9;                 // 0..3 = ks*2 + t
            int t  = slot & 1;
            int ks = slot >> 1;
            int o  = t * 16 + (lane & 15);
            int c  = ks * 32 + (lane >> 4) * 8 + j;
            woffr[idx] = (o < 18) ? (unsigned short)f2bf(w_off[o * Cn + c]) : 0;
        }
        return;
    }

    // ---- transpose: 64px x 64ch tile, 4x4 register micro-transpose ----
    __shared__ __align__(16) float tile[64 * TLP];             // 17408 B
    const int b   = bid >> 8;
    const int px0 = (bid & 255) << 6;

    {   // phase A: (pg,cq) loads 4ch x 4px, writes 4 x b128 rows
        const int pg = tid & 15;           // 4-px group
        const int cq = tid >> 4;           // 4-ch group
        const float* xp = x + (size_t)b * (Cn * HWn) + px0 + pg * 4;
        float4 v[4];
#pragma unroll
        for (int i = 0; i < 4; i++)
            v[i] = *(const float4*)(xp + (size_t)(cq * 4 + i) * HWn);
#pragma unroll
        for (int j = 0; j < 4; j++)
            *(float4*)&tile[(pg * 4 + j) * TLP + cq * 4] =
                make_float4((&v[0].x)[j], (&v[1].x)[j],
                            (&v[2].x)[j], (&v[3].x)[j]);
    }
    __syncthreads();
    {   // phase B: (cf4,r) reads b128, packs 2 dwords (exact RNE), uint2 store
        const int cf4 = tid & 15;          // 4-channel group
        const int r   = tid >> 4;          // 0-15
        unsigned* dst = xT + ((size_t)b * HWn + px0) * 32;
#pragma unroll
        for (int j = 0; j < 4; j++) {
            const int p = j * 16 + r;
            const float4 t4 = *(const float4*)&tile[p * TLP + cf4 * 4];
            *(uint2*)(dst + p * 32 + cf4 * 2) =
                make_uint2(pkbf(t4.x, t4.y), pkbf(t4.z, t4.w));
        }
    }
}

// ---------------------------------------------------------------------------
// Main kernel: R10 data path with ONE scheduling change (R13 = T14 split).
//
// R13 theory: in R10, the wt2 staging at the top of each k is
// global_load + ds_write fused -> the compiler's vmcnt wait before the
// ds_write stalls each wave ~L2 latency at the top of EVERY k, and that
// ds_write then sits in the lgkm queue that the mid-iteration drain waits
// on.  Fix (issue-early/write-late): load staging data to REGISTERS at the
// top; ds_write it to wtl[nxt] AFTER the MFMA block (data has ~600cy to
// land -> vmcnt wait free; mid-iteration lgkm drain covers only the 2
// chunk writes).  Cross-wave safety unchanged: write(wtl[nxt],k) ->
// __syncthreads -> read(wtl[nxt],k+1), the R9/R10-verified discipline.
// Session ledger: f32x2 packed combine ABANDONED (4 corrupt rounds);
// single-buffer chunk reuse abandoned; same-half bpermute correct but
// slower (R11: pair-major halves TA merge); sp-major 64B gather merge is
// non-negotiable; occupancy knobs null (R3/R7); wt2 LDS dedup verified R9;
// pkbf2+mktap-lite verified R10; prep micro-transpose verified R12.
// ---------------------------------------------------------------------------
struct Tap { float w00, w01, w10, w11; int c00, c01, c10, c11; };

__device__ __forceinline__ Tap mktap(int k, float offy, float offx, int h, int w) {
    Tap s;
    const int kh = k / 3, kw = k - kh * 3;
    const float py  = (float)(h - 1 + kh) + offy;
    const float pxf = (float)(w - 1 + kw) + offx;
    const float y0f = floorf(py), x0f = floorf(pxf);
    const float wy1 = py - y0f, wx1 = pxf - x0f;
    const float wy0 = 1.f - wy1, wx0 = 1.f - wx1;
    const int y0 = (int)y0f, x0i = (int)x0f;
    const int y1 = y0 + 1,  x1 = x0i + 1;
    const float zy0 = ((unsigned)y0  < (unsigned)Hn) ? wy0 : 0.f;
    const float zy1 = ((unsigned)y1  < (unsigned)Hn) ? wy1 : 0.f;
    const float zx0 = ((unsigned)x0i < (unsigned)Wn) ? wx0 : 0.f;
    const float zx1 = ((unsigned)x1  < (unsigned)Wn) ? wx1 : 0.f;
    s.w00 = zy0 * zx0; s.w01 = zy0 * zx1;
    s.w10 = zy1 * zx0; s.w11 = zy1 * zx1;
    const int yc0 = min(max(y0, 0), Hn - 1), yc1 = min(max(y1, 0), Hn - 1);
    const int xc0 = min(max(x0i, 0), Wn - 1), xc1 = min(max(x1, 0), Wn - 1);
    s.c00 = (yc0 * Wn + xc0) * 32; s.c01 = (yc0 * Wn + xc1) * 32;
    s.c10 = (yc1 * Wn + xc0) * 32; s.c11 = (yc1 * Wn + xc1) * 32;
    return s;
}

__device__ __forceinline__ void combine4(unsigned* dst, const uint4* u, const Tap& s) {
#pragma unroll
    for (int i = 0; i < 4; i++) {
        const unsigned a = (&u[0].x)[i], b = (&u[1].x)[i];
        const unsigned c = (&u[2].x)[i], d = (&u[3].x)[i];
        const float slo = s.w00 * bflo(a) + s.w01 * bflo(b)
                        + s.w10 * bflo(c) + s.w11 * bflo(d);
        const float shi = s.w00 * bfhi(a) + s.w01 * bfhi(b)
                        + s.w10 * bfhi(c) + s.w11 * bfhi(d);
        dst[i] = pkbf2(slo, shi);
    }
}

__device__ __forceinline__ void gather8(uint4* u, const unsigned* xb,
                                        const Tap& s, int c2) {
    const unsigned* g00 = xb + s.c00 + c2 * 4;
    const unsigned* g01 = xb + s.c01 + c2 * 4;
    const unsigned* g10 = xb + s.c10 + c2 * 4;
    const unsigned* g11 = xb + s.c11 + c2 * 4;
    u[0] = *(const uint4*)g00;          // half 0: chunk c2   (ks=0)
    u[1] = *(const uint4*)g01;
    u[2] = *(const uint4*)g10;
    u[3] = *(const uint4*)g11;
    u[4] = *(const uint4*)(g00 + 16);   // half 1: chunk 4+c2 (ks=1)
    u[5] = *(const uint4*)(g01 + 16);
    u[6] = *(const uint4*)(g10 + 16);
    u[7] = *(const uint4*)(g11 + 16);
}

__global__ __launch_bounds__(256, 2) void dcn_kernel(
        const unsigned* __restrict__ xT,
        const unsigned short* __restrict__ wt2,
        const unsigned short* __restrict__ woffr,
        const float* __restrict__ b_off,
        float* __restrict__ out) {
    // chunk tiles (first 5120 B double as offl during the prologue, R7-
    // verified) + double-buffered wt2 B-matrix stage (2 x 8192 B)
    __shared__ __align__(16) unsigned shmem[4][2][16 * 36];    // 18432 B
    __shared__ __align__(16) unsigned short wtl[2][8 * 512];   // 16384 B
    float* const offl = (float*)&shmem[0][0][0];               // prologue alias

    const int tid = threadIdx.x;
    const int bid = blockIdx.x;
    // XCD swizzle: bid&7 = image -> per-XCD L2 holds one 2.1MB bf16 image
    const int logical = ((bid & 7) << 8) | (bid >> 3);         // 2048 blocks
    const int b   = logical >> 8;
    const int hw0 = (logical & 255) << 6;

    const int lane = tid & 63;
    const int wv   = tid >> 6;
    const int q    = lane >> 4;        // consumer: chunk index / K-half group
    const int sp   = lane & 15;        // consumer + prologue pixel
    const int m    = lane >> 2;        // producer pixel (sp-major gather)
    const int c2   = lane & 3;         // producer 16B-chunk within 64B half
    const int pix0 = hw0 + wv * 16;
    const int pix  = pix0 + sp;

    const unsigned* xb = xT + (size_t)b * (HWn * 32);          // uint = 2 channels

    // ---- offset conv via MFMA (R6-verified) ------------------------------
    {
        union { uint4 u; bf16x8 v; } aw0, aw1;
        aw0.u = *(const uint4*)(xb + pix * 32 + q * 4);
        aw1.u = *(const uint4*)(xb + pix * 32 + 16 + q * 4);
        f32x4 oa0 = (f32x4){0.f, 0.f, 0.f, 0.f};
        f32x4 oa1 = (f32x4){0.f, 0.f, 0.f, 0.f};
        const bf16x8 bo00 = *(const bf16x8*)(woffr + 0 * 512 + lane * 8);
        const bf16x8 bo01 = *(const bf16x8*)(woffr + 1 * 512 + lane * 8);
        const bf16x8 bo10 = *(const bf16x8*)(woffr + 2 * 512 + lane * 8);
        const bf16x8 bo11 = *(const bf16x8*)(woffr + 3 * 512 + lane * 8);
        oa0 = __builtin_amdgcn_mfma_f32_16x16x32_bf16(aw0.v, bo00, oa0, 0, 0, 0);
        oa1 = __builtin_amdgcn_mfma_f32_16x16x32_bf16(aw0.v, bo01, oa1, 0, 0, 0);
        oa0 = __builtin_amdgcn_mfma_f32_16x16x32_bf16(aw1.v, bo10, oa0, 0, 0, 0);
        oa1 = __builtin_amdgcn_mfma_f32_16x16x32_bf16(aw1.v, bo11, oa1, 0, 0, 0);
        const int oc = lane & 15, rg = lane >> 4;
        float* ol = offl + wv * (16 * OLP);
        const float bo_a = b_off[oc];
#pragma unroll
        for (int r = 0; r < 4; r++)
            ol[(rg * 4 + r) * OLP + oc] = oa0[r] + bo_a;
        if (oc < 2) {
            const float bo_b = b_off[16 + oc];
#pragma unroll
            for (int r = 0; r < 4; r++)
                ol[(rg * 4 + r) * OLP + 16 + oc] = oa1[r] + bo_b;
        }
    }
    // stage wt2[k=0] into wtl[0] at 16B lane stride (R10-verified pattern;
    // prologue is not latency-critical, fused load+write is fine here)
    {
        const uint4* s0 = (const uint4*)(wt2);
        uint4* d0 = (uint4*)(&wtl[0][0]);
        d0[tid]       = s0[tid];
        d0[tid + 256] = s0[tid + 256];
    }
    asm volatile("s_waitcnt lgkmcnt(0)" ::: "memory");   // per-wave LDS hand-off

    // hoist this lane's 18 offsets (pixel m) into registers (R2/R7-verified)
    const float* olp = offl + wv * (16 * OLP) + m * OLP;
    float off[18];
#pragma unroll
    for (int i = 0; i < 9; i++) {
        const float2 o2 = *(const float2*)(olp + 2 * i);
        off[2 * i]     = o2.x;
        off[2 * i + 1] = o2.y;
    }

    // cross-wave barrier: all offl reads done before chunk writes; wtl[0]
    // staging visible to all waves
    __syncthreads();

    // producer-side state: this lane samples pixel m
    const int pixm = pix0 + m;
    const int hm = pixm >> 7;
    const int wm = pixm & 127;
    unsigned* cwv = &shmem[wv][0][0];                    // 2 x 576 dwords

    f32x4 acc[4];
#pragma unroll
    for (int t = 0; t < 4; t++) acc[t] = (f32x4){0.f, 0.f, 0.f, 0.f};

    // ---- software pipeline state: gather regs for k=0 (R2/R8-verified) ---
    uint4 u[2][8];                     // ping-pong gather state
    Tap   tp[2];
    tp[0] = mktap(0, off[0], off[1], hm, wm);
    gather8(u[0], xb, tp[0], c2);

#pragma unroll
    for (int k = 0; k < K2n; k++) {
        const int cur = k & 1, nxt = cur ^ 1;

        // ---- T14 issue-early: staging loads to REGISTERS only (no
        //      ds_write here -> no vmcnt stall at top of iteration), plus
        //      k+1's gathers ----
        uint4 wr0, wr1;
        if (k + 1 < K2n) {
            const uint4* sn = (const uint4*)(wt2 + (size_t)(k + 1) * 4096);
            wr0 = sn[tid];
            wr1 = sn[tid + 256];
            tp[nxt] = mktap(k + 1, off[2 * k + 2], off[2 * k + 3], hm, wm);
            gather8(u[nxt], xb, tp[nxt], c2);
        }

        // combine current k's taps + pack
        unsigned A0[4], A1[4];
        combine4(A0, &u[cur][0], tp[cur]);  // channels c2*8..+8      (ks=0)
        combine4(A1, &u[cur][4], tp[cur]);  // channels 32+c2*8..+8   (ks=1)

        // redistribute via double-buffered wave-private chunk LDS
        unsigned* cb = cwv + cur * 576;
        *(uint4*)(cb + m * 36 + c2 * 4)      = make_uint4(A0[0], A0[1], A0[2], A0[3]);
        *(uint4*)(cb + m * 36 + 16 + c2 * 4) = make_uint4(A1[0], A1[1], A1[2], A1[3]);

        // RAW: commit chunk writes before frag reads (drain now covers ONLY
        // the 2 chunk writes -- staging ds_write moved below the MFMAs)
        asm volatile("s_waitcnt lgkmcnt(0)" ::: "memory");

        const bf16x8 af0 = *(const bf16x8*)(cb + sp * 36 + q * 4);
        const bf16x8 af1 = *(const bf16x8*)(cb + sp * 36 + 16 + q * 4);

        // B-frags from the block-shared LDS stage (R9-verified)
        const unsigned short* bl = &wtl[cur][lane * 8];
#pragma unroll
        for (int t = 0; t < 4; t++) {
            const bf16x8 b0 = *(const bf16x8*)(bl + t * 512);
            acc[t] = __builtin_amdgcn_mfma_f32_16x16x32_bf16(af0, b0, acc[t], 0, 0, 0);
            const bf16x8 b1 = *(const bf16x8*)(bl + (4 + t) * 512);
            acc[t] = __builtin_amdgcn_mfma_f32_16x16x32_bf16(af1, b1, acc[t], 0, 0, 0);
        }

        // ---- T14 write-late: staging global data has had the whole
        //      iteration to land -> vmcnt wait before these ds_writes is
        //      free.  wtl[nxt]'s previous read (iteration k-1) is separated
        //      from this write by the k-1 bottom barrier (verified
        //      discipline).  The barrier below publishes it for k+1. ----
        if (k + 1 < K2n) {
            uint4* dn = (uint4*)(&wtl[nxt][0]);
            dn[tid]       = wr0;
            dn[tid + 256] = wr1;
        }
        __syncthreads();
    }

    // ---- epilogue: C/D layout col(=o)=lane&15, row(=px)=(lane>>4)*4+r ----
    const int oc = lane & 15;
    const int rg = lane >> 4;
    float* ob = out + (size_t)b * (On * HWn) + pix0 + rg * 4;
#pragma unroll
    for (int t = 0; t < 4; t++) {
        const int o = t * 16 + oc;
        *(f32x4*)(ob + (size_t)o * HWn) = acc[t];
    }
}

// ---------------------------------------------------------------------------
extern "C" void kernel_launch(void* const* d_in, const int* in_sizes, int n_in,
                              void* d_out, int out_size, void* d_ws, size_t ws_size,
                              hipStream_t stream) {
    const float* x      = (const float*)d_in[0];   // (8,64,128,128)
    const float* weight = (const float*)d_in[1];   // (64,64,3,3)
    const float* w_off  = (const float*)d_in[2];   // (18,64)
    const float* b_off  = (const float*)d_in[3];   // (18,)
    float* out = (float*)d_out;                    // (8,64,128,128)

    // workspace: xT 16 MB | wt2 73728 B | woffr 4096 B
    unsigned*       xT    = (unsigned*)d_ws;
    unsigned short* wt2   = (unsigned short*)((char*)d_ws + 16777216);
    unsigned short* woffr = (unsigned short*)((char*)d_ws + 16777216 + 73728);

    prep_kernel<<<2200, 256, 0, stream>>>(x, weight, w_off, xT, wt2, woffr);
    dcn_kernel<<<2048, 256, 0, stream>>>(xT, wt2, woffr, b_off, out);
}